// Round 20
// baseline (754.076 us; speedup 1.0000x reference)
//
#include <hip/hip_runtime.h>
#include <hip/hip_bf16.h>
#include <cstdint>
#include <cstddef>

#define NP_N 20000
#define NA_N 20000
#define E_AP_N 400000
#define E_PP_N 400000
// D_IN=128, D_H=256, HEADS=8, D_HEAD=32, D_FF=2048, D_OUT=64

typedef __attribute__((ext_vector_type(8))) short bf16x8;
typedef __attribute__((ext_vector_type(4))) float f32x4;

__device__ __forceinline__ float b2f(ushort u) { return __uint_as_float(((uint32_t)u) << 16); }
__device__ __forceinline__ ushort f2b(float f) {
    uint32_t x = __float_as_uint(f);
    return (ushort)((x + 0x7fffu + ((x >> 16) & 1u)) >> 16);  // RNE (no NaN inputs here)
}

#define LGKM_BARRIER() do { \
    asm volatile("s_waitcnt lgkmcnt(0)" ::: "memory"); \
    __builtin_amdgcn_s_barrier(); \
    __builtin_amdgcn_sched_barrier(0); \
} while (0)

// ---------------------------------------------------------------------------
// Mega pack kernel (converts + weight packs + counter zero), one dispatch.
// types: 0=packB gemm order, 1=packW1 ff, 2=packW2 ff, 3=cvt, 4=zero int4
// ---------------------------------------------------------------------------
#define NJOBS 14
struct PackJobs {
    const float* src[NJOBS];
    void* dst[NJOBS];
    int M[NJOBS], K[NJOBS];
    int type[NJOBS];
    int nquad[NJOBS];
    int blk0[NJOBS];
};

__global__ void pack_all_kernel(PackJobs J)
{
    int b = blockIdx.x;
    int j = 0;
    while (j + 1 < NJOBS && b >= J.blk0[j + 1]) ++j;
    int u = (b - J.blk0[j]) * 256 + threadIdx.x;
    if (u >= J.nquad[j]) return;
    int ty = J.type[j];
    const float* src = J.src[j];
    if (ty == 3) {
        float4 v = ((const float4*)src)[u];
        ushort4 o;
        o.x = f2b(v.x); o.y = f2b(v.y); o.z = f2b(v.z); o.w = f2b(v.w);
        ((ushort4*)J.dst[j])[u] = o;
    } else if (ty == 4) {
        int4 z = {0, 0, 0, 0};
        ((int4*)J.dst[j])[u] = z;
    } else if (ty == 0) {
        // out[(jt*KT+t)*4096 + ks*1024 + r*8 + e] = B[jt*128+r][t*32+ks*8+e]
        int M = J.M[j], K = J.K[j];
        int KT = K >> 5;
        int q = u & 1023;
        int jt = u >> 10;
        int t = jt % KT, jj = jt / KT;
        int ks = q >> 8, rem = q & 255;
        int r = rem >> 1;
        int e0 = (rem & 1) * 4;
        int row = jj * 128 + r;
        ushort4 o = {0, 0, 0, 0};
        if (row < M) {
            const float* s = src + (size_t)row * K + t * 32 + ks * 8 + e0;
            o.x = f2b(s[0]); o.y = f2b(s[1]); o.z = f2b(s[2]); o.w = f2b(s[3]);
        }
        ((ushort4*)J.dst[j])[u] = o;
    } else if (ty == 1) {
        // W1(2048,256) -> [chunk32f][s32][f32][8]
        int q = u & 2047, chunk = u >> 11;
        int s = q >> 6, rem = q & 63;
        int fl = rem >> 1, e0 = (rem & 1) * 4;
        const float* sp = src + (size_t)(chunk * 32 + fl) * 256 + s * 8 + e0;
        ushort4 o;
        o.x = f2b(sp[0]); o.y = f2b(sp[1]); o.z = f2b(sp[2]); o.w = f2b(sp[3]);
        ((ushort4*)J.dst[j])[u] = o;
    } else {
        // W2(256,2048) -> [chunk32f][s2 4][c256][8]
        int q = u & 2047, chunk = u >> 11;
        int s2 = q >> 9, rem = q & 511;
        int c = rem >> 1, e0 = (rem & 1) * 4;
        const float* sp = src + (size_t)c * 2048 + chunk * 32 + s2 * 8 + e0;
        ushort4 o;
        o.x = f2b(sp[0]); o.y = f2b(sp[1]); o.z = f2b(sp[2]); o.w = f2b(sp[3]);
        ((ushort4*)J.dst[j])[u] = o;
    }
}

// ---------------------------------------------------------------------------
// Shared GEMM K-loop body (bf16 out): C(N,M)=A(N,K)@Bp^T+bias at (row0,col0).
// ---------------------------------------------------------------------------
__device__ __forceinline__ void gemm_body_bf16(
    ushort* Ab, ushort* Bb,   // LDS: 3*4096 each
    const ushort* A, const ushort* Bp, const float* bias, ushort* C,
    int N, int M, int K, int lda, int ldc, int row0, int col0)
{
    const int tid = threadIdx.x;
    const int lane = tid & 63;
    const int w = tid >> 6;
    const int wr = w >> 1, wc = w & 1;
    const int KT = K >> 5;
    const ushort* Bbase = Bp + (size_t)(col0 >> 7) * KT * 4096;
    f32x4 acc[4][4] = {};

    size_t aoff[2];
#pragma unroll
    for (int i = 0; i < 2; ++i) {
        int r = row0 + i * 64 + lane;
        if (r > N - 1) r = N - 1;
        aoff[i] = (size_t)r * lda + w * 8;
    }

    auto stage = [&](int buf, int t) {
        const int k0 = t << 5;
#pragma unroll
        for (int i = 0; i < 2; ++i) {
            __builtin_amdgcn_global_load_lds(
                (const __attribute__((address_space(1))) void*)(A + aoff[i] + k0),
                (__attribute__((address_space(3))) void*)(&Ab[buf * 4096 + (w * 2 + i) * 512]), 16, 0, 0);
        }
#pragma unroll
        for (int i = 0; i < 2; ++i) {
            __builtin_amdgcn_global_load_lds(
                (const __attribute__((address_space(1))) void*)(Bbase + (size_t)t * 4096 + (w * 2 + i) * 512 + lane * 8),
                (__attribute__((address_space(3))) void*)(&Bb[buf * 4096 + (w * 2 + i) * 512]), 16, 0, 0);
        }
    };

    stage(0, 0);
    stage(1, 1);

    int cur = 0;
    for (int t = 0; t < KT; ++t) {
        if (t + 1 < KT) { asm volatile("s_waitcnt vmcnt(4)" ::: "memory"); }
        else            { asm volatile("s_waitcnt vmcnt(0)" ::: "memory"); }
        __builtin_amdgcn_s_barrier();
        __builtin_amdgcn_sched_barrier(0);
        if (t + 2 < KT) {
            int nb = cur - 1; if (nb < 0) nb = 2;   // (t+2)%3
            stage(nb, t + 2);
        }

        bf16x8 af[4], bfr[4];
        const int ks = lane >> 4;
        const int rl = lane & 15;
#pragma unroll
        for (int m = 0; m < 4; ++m)
            af[m] = *(const bf16x8*)&Ab[cur * 4096 + ks * 1024 + (wr * 64 + m * 16 + rl) * 8];
#pragma unroll
        for (int n = 0; n < 4; ++n)
            bfr[n] = *(const bf16x8*)&Bb[cur * 4096 + ks * 1024 + (wc * 64 + n * 16 + rl) * 8];
#pragma unroll
        for (int m = 0; m < 4; ++m)
#pragma unroll
            for (int n = 0; n < 4; ++n)
                acc[m][n] = __builtin_amdgcn_mfma_f32_16x16x32_bf16(af[m], bfr[n], acc[m][n], 0, 0, 0);

        cur = (cur == 2) ? 0 : cur + 1;
    }

#pragma unroll
    for (int m = 0; m < 4; ++m) {
#pragma unroll
        for (int n = 0; n < 4; ++n) {
            int gc = col0 + wc * 64 + n * 16 + (lane & 15);
            if (gc >= M) continue;
            float bv = bias ? bias[gc] : 0.f;
#pragma unroll
            for (int r = 0; r < 4; ++r) {
                int grow = row0 + wr * 64 + m * 16 + (lane >> 4) * 4 + r;
                if (grow >= N) continue;
                C[(size_t)grow * ldc + gc] = f2b(acc[m][n][r] + bv);
            }
        }
    }
}

// ---------------------------------------------------------------------------
// Single GEMM (bf16 or f32 out) — used for qkv_s and prediction head.
// OUT_MODE: 0 = bf16, 1 = f32
// ---------------------------------------------------------------------------
template <int OUT_MODE>
__global__ __launch_bounds__(256) void gemm_mfma(
    const ushort* __restrict__ A, const ushort* __restrict__ Bp,
    const float* __restrict__ bias, void* __restrict__ Cv,
    int N, int M, int K, int lda, int ldc)
{
    __shared__ __align__(16) ushort Ab[3 * 4096];
    __shared__ __align__(16) ushort Bb[3 * 4096];
    if (OUT_MODE == 0) {
        gemm_body_bf16(Ab, Bb, A, Bp, bias, (ushort*)Cv, N, M, K, lda, ldc,
                       blockIdx.x * 128, blockIdx.y * 128);
        return;
    }
    // f32-out path (pred head), same loop
    const int tid = threadIdx.x;
    const int lane = tid & 63;
    const int w = tid >> 6;
    const int wr = w >> 1, wc = w & 1;
    const int row0 = blockIdx.x * 128;
    const int col0 = blockIdx.y * 128;
    const int KT = K >> 5;
    const ushort* Bbase = Bp + (size_t)blockIdx.y * KT * 4096;
    f32x4 acc[4][4] = {};

    size_t aoff[2];
#pragma unroll
    for (int i = 0; i < 2; ++i) {
        int r = row0 + i * 64 + lane;
        if (r > N - 1) r = N - 1;
        aoff[i] = (size_t)r * lda + w * 8;
    }

    auto stage = [&](int buf, int t) {
        const int k0 = t << 5;
#pragma unroll
        for (int i = 0; i < 2; ++i) {
            __builtin_amdgcn_global_load_lds(
                (const __attribute__((address_space(1))) void*)(A + aoff[i] + k0),
                (__attribute__((address_space(3))) void*)(&Ab[buf * 4096 + (w * 2 + i) * 512]), 16, 0, 0);
        }
#pragma unroll
        for (int i = 0; i < 2; ++i) {
            __builtin_amdgcn_global_load_lds(
                (const __attribute__((address_space(1))) void*)(Bbase + (size_t)t * 4096 + (w * 2 + i) * 512 + lane * 8),
                (__attribute__((address_space(3))) void*)(&Bb[buf * 4096 + (w * 2 + i) * 512]), 16, 0, 0);
        }
    };

    stage(0, 0);
    stage(1, 1);

    int cur = 0;
    for (int t = 0; t < KT; ++t) {
        if (t + 1 < KT) { asm volatile("s_waitcnt vmcnt(4)" ::: "memory"); }
        else            { asm volatile("s_waitcnt vmcnt(0)" ::: "memory"); }
        __builtin_amdgcn_s_barrier();
        __builtin_amdgcn_sched_barrier(0);
        if (t + 2 < KT) {
            int nb = cur - 1; if (nb < 0) nb = 2;
            stage(nb, t + 2);
        }

        bf16x8 af[4], bfr[4];
        const int ks = lane >> 4;
        const int rl = lane & 15;
#pragma unroll
        for (int m = 0; m < 4; ++m)
            af[m] = *(const bf16x8*)&Ab[cur * 4096 + ks * 1024 + (wr * 64 + m * 16 + rl) * 8];
#pragma unroll
        for (int n = 0; n < 4; ++n)
            bfr[n] = *(const bf16x8*)&Bb[cur * 4096 + ks * 1024 + (wc * 64 + n * 16 + rl) * 8];
#pragma unroll
        for (int m = 0; m < 4; ++m)
#pragma unroll
            for (int n = 0; n < 4; ++n)
                acc[m][n] = __builtin_amdgcn_mfma_f32_16x16x32_bf16(af[m], bfr[n], acc[m][n], 0, 0, 0);

        cur = (cur == 2) ? 0 : cur + 1;
    }

#pragma unroll
    for (int m = 0; m < 4; ++m) {
#pragma unroll
        for (int n = 0; n < 4; ++n) {
            int gc = col0 + wc * 64 + n * 16 + (lane & 15);
            if (gc >= M) continue;
            float bv = bias ? bias[gc] : 0.f;
#pragma unroll
            for (int r = 0; r < 4; ++r) {
                int grow = row0 + wr * 64 + m * 16 + (lane >> 4) * 4 + r;
                if (grow >= N) continue;
                ((float*)Cv)[(size_t)grow * ldc + gc] = acc[m][n][r] + bv;
            }
        }
    }
}

static inline void gemm_bf(const ushort* A, const ushort* Bp, const float* bias, void* C,
                           int N, int M, int K, int lda, int ldc, int mode, hipStream_t s)
{
    dim3 g((N + 127) / 128, (M + 127) / 128);
    if (mode == 0) gemm_mfma<0><<<g, 256, 0, s>>>(A, Bp, bias, C, N, M, K, lda, ldc);
    else           gemm_mfma<1><<<g, 256, 0, s>>>(A, Bp, bias, C, N, M, K, lda, ldc);
}

// ---------------------------------------------------------------------------
// Batched GEMM: up to 3 independent bf16-out GEMMs in one dispatch.
// ---------------------------------------------------------------------------
#define GNJ 3
struct GemmJobs {
    const ushort* A[GNJ];
    const ushort* Bp[GNJ];
    const float* bias[GNJ];
    ushort* C[GNJ];
    int N[GNJ], M[GNJ], K[GNJ], lda[GNJ], ldc[GNJ];
    int blk0[GNJ], nbx[GNJ];
    int njobs;
};

__global__ __launch_bounds__(256) void gemm_batch_kernel(GemmJobs G)
{
    __shared__ __align__(16) ushort Ab[3 * 4096];
    __shared__ __align__(16) ushort Bb[3 * 4096];
    int b = blockIdx.x;
    int j = 0;
    while (j + 1 < G.njobs && b >= G.blk0[j + 1]) ++j;
    int lb = b - G.blk0[j];
    int bx = lb % G.nbx[j];
    int by = lb / G.nbx[j];
    gemm_body_bf16(Ab, Bb, G.A[j], G.Bp[j], G.bias[j], G.C[j],
                   G.N[j], G.M[j], G.K[j], G.lda[j], G.ldc[j], bx * 128, by * 128);
}

// ---------------------------------------------------------------------------
// Fused o-proj + residual + LayerNorm:  X <- LayerNorm(res + o @ Wo^T + bo)
// ---------------------------------------------------------------------------
__global__ __launch_bounds__(256, 2) void proj_ln_kernel(
    const ushort* o, int ldo,
    const ushort* __restrict__ Bp, const float* __restrict__ bo,
    const ushort* res, int ldr,
    const float* __restrict__ g, const float* __restrict__ be,
    ushort* X, int N)
{
    __shared__ __align__(16) ushort Wb[8192];   // [tile2][ks4][r128][8] 16KB
    const int tid = threadIdx.x;
    const int lane = tid & 63;
    const int w = tid >> 6;
    const int wr = w >> 1, wc = w & 1;
    const int row0 = blockIdx.x * 64;
    const int rl = lane & 15;
    const int ks = lane >> 4;

    int arow[2];
#pragma unroll
    for (int m = 0; m < 2; ++m) {
        int r = row0 + wr * 32 + m * 16 + rl;
        arow[m] = (r < N) ? r : (N - 1);
    }

    f32x4 oacc[2][8] = {};

    for (int t = 0; t < 8; ++t) {
#pragma unroll
        for (int i = 0; i < 4; ++i) {
            int ii = w * 4 + i;   // 0..15
            const ushort* src = Bp + ((size_t)(ii >> 3) * 8 + t) * 4096 + (ii & 7) * 512 + lane * 8;
            __builtin_amdgcn_global_load_lds(
                (const __attribute__((address_space(1))) void*)src,
                (__attribute__((address_space(3))) void*)(&Wb[ii * 512]), 16, 0, 0);
        }
        bf16x8 af[2];
#pragma unroll
        for (int m = 0; m < 2; ++m)
            af[m] = *(const bf16x8*)(o + (size_t)arow[m] * ldo + t * 32 + ks * 8);
        __syncthreads();

#pragma unroll
        for (int n = 0; n < 8; ++n) {
            bf16x8 bfr = *(const bf16x8*)&Wb[wc * 4096 + ks * 1024 + (n * 16 + rl) * 8];
#pragma unroll
            for (int m = 0; m < 2; ++m)
                oacc[m][n] = __builtin_amdgcn_mfma_f32_16x16x32_bf16(af[m], bfr, oacc[m][n], 0, 0, 0);
        }
        __syncthreads();
    }

    float2* lnb = (float2*)Wb;
    float psum[2][4] = {}, psq[2][4] = {};
#pragma unroll
    for (int n = 0; n < 8; ++n) {
        int c = wc * 128 + n * 16 + rl;
        float bv = bo[c];
#pragma unroll
        for (int m = 0; m < 2; ++m)
#pragma unroll
            for (int r = 0; r < 4; ++r) {
                int grow = row0 + wr * 32 + m * 16 + ks * 4 + r;
                float v = oacc[m][n][r] + bv + b2f(res[(size_t)grow * ldr + c]);
                oacc[m][n][r] = v;
                psum[m][r] += v;
                psq[m][r] = fmaf(v, v, psq[m][r]);
            }
    }
#pragma unroll
    for (int off = 8; off >= 1; off >>= 1)
#pragma unroll
        for (int m = 0; m < 2; ++m)
#pragma unroll
            for (int r = 0; r < 4; ++r) {
                psum[m][r] += __shfl_xor(psum[m][r], off);
                psq[m][r]  += __shfl_xor(psq[m][r], off);
            }
    if (rl == 0) {
#pragma unroll
        for (int m = 0; m < 2; ++m)
#pragma unroll
            for (int r = 0; r < 4; ++r) {
                int lr = wr * 32 + m * 16 + ks * 4 + r;
                lnb[wc * 64 + lr] = make_float2(psum[m][r], psq[m][r]);
            }
    }
    __syncthreads();
    float mean_[2][4], rstd_[2][4];
#pragma unroll
    for (int m = 0; m < 2; ++m)
#pragma unroll
        for (int r = 0; r < 4; ++r) {
            int lr = wr * 32 + m * 16 + ks * 4 + r;
            float2 a0 = lnb[lr], a1 = lnb[64 + lr];
            float mean = (a0.x + a1.x) * (1.f / 256.f);
            float var = (a0.y + a1.y) * (1.f / 256.f) - mean * mean;
            mean_[m][r] = mean;
            rstd_[m][r] = rsqrtf(var + 1e-5f);
        }
#pragma unroll
    for (int n = 0; n < 8; ++n) {
        int c = wc * 128 + n * 16 + rl;
        float gv = g[c], bev = be[c];
#pragma unroll
        for (int m = 0; m < 2; ++m)
#pragma unroll
            for (int r = 0; r < 4; ++r) {
                int grow = row0 + wr * 32 + m * 16 + ks * 4 + r;
                if (grow < N)
                    X[(size_t)grow * 256 + c] =
                        f2b((oacc[m][n][r] - mean_[m][r]) * rstd_[m][r] * gv + bev);
            }
    }
}

// ---------------------------------------------------------------------------
// Fused FF + residual + LN3 v9: T14 async-stage (global->reg prefetch,
// ds_write publish), lgkm-only barriers — weight loads for chunk fc+1 stay
// in flight across chunk fc's entire compute. X in place.
// ---------------------------------------------------------------------------
__global__ __launch_bounds__(256, 2) void ff_ln_kernel(
    const ushort* __restrict__ W1p, const ushort* __restrict__ W2p,
    const float* __restrict__ b1, const float* __restrict__ b2,
    const float* __restrict__ g3, const float* __restrict__ be3,
    ushort* X, int N)
{
    __shared__ __align__(16) ushort W1buf[8192];  // [s32][f32][8]   16KB
    __shared__ __align__(16) ushort W2buf[8192];  // [s2 4][c256][8] 16KB
    __shared__ __align__(16) ushort Sbuf[2048];   // [s 4][row64][8]  4KB
    const int tid = threadIdx.x;
    const int lane = tid & 63;
    const int w = tid >> 6;
    const int wr = w >> 1, wc = w & 1;
    const int row0 = blockIdx.x * 64;
    const int rl = lane & 15;
    const int ks = lane >> 4;

    bf16x8 xf[2][8];
#pragma unroll
    for (int m = 0; m < 2; ++m) {
        int gr = row0 + wr * 32 + m * 16 + rl;
        if (gr > N - 1) gr = N - 1;
        const ushort* xrow = X + (size_t)gr * 256 + ks * 8;
#pragma unroll
        for (int kc = 0; kc < 8; ++kc)
            xf[m][kc] = *(const bf16x8*)(xrow + kc * 32);
    }

    f32x4 oacc[2][8] = {};

    // reg-staged weights: 8 x 16B per thread = one 32KB chunk per block
    bf16x8 wreg[8];
    auto ldregs = [&](int fc) {
#pragma unroll
        for (int i = 0; i < 8; ++i) {
            int ii = w * 8 + i;  // 0..31: 16 W1 pieces then 16 W2 pieces
            const ushort* src = (ii < 16)
                ? W1p + (size_t)fc * 8192 + ii * 512 + lane * 8
                : W2p + (size_t)fc * 8192 + (ii - 16) * 512 + lane * 8;
            wreg[i] = *(const bf16x8*)src;
        }
    };
    ldregs(0);

    for (int fc = 0; fc < 64; ++fc) {
        // ---- publish staged regs to LDS (compiler waits vmcnt on wreg) ----
#pragma unroll
        for (int i = 0; i < 8; ++i) {
            int ii = w * 8 + i;
            ushort* dst = (ii < 16) ? &W1buf[ii * 512 + lane * 8]
                                    : &W2buf[(ii - 16) * 512 + lane * 8];
            *(bf16x8*)dst = wreg[i];
        }
        LGKM_BARRIER();                     // weights visible to all waves
        if (fc + 1 < 64) ldregs(fc + 1);    // prefetch next chunk, in flight

        // ---- phase A (swapped): S[f][row] = relu(W1c @ X^T + b1) ----
        f32x4 sacc[2] = {};
#pragma unroll
        for (int kc = 0; kc < 8; ++kc) {
            bf16x8 w1f = *(const bf16x8*)&W1buf[(kc * 4 + ks) * 256 + (wc * 16 + rl) * 8];
#pragma unroll
            for (int m = 0; m < 2; ++m)
                sacc[m] = __builtin_amdgcn_mfma_f32_16x16x32_bf16(w1f, xf[m][kc], sacc[m], 0, 0, 0);
        }
        {
            const int f0 = fc * 32;
            const int fb = wc * 16 + ks * 4;
            const int sidx = wc * 2 + (ks >> 1);
            const int e0 = (ks & 1) * 4;
            float4 b1v = *(const float4*)&b1[f0 + fb];
#pragma unroll
            for (int m = 0; m < 2; ++m) {
                ushort4 o;
                o.x = f2b(fmaxf(sacc[m][0] + b1v.x, 0.f));
                o.y = f2b(fmaxf(sacc[m][1] + b1v.y, 0.f));
                o.z = f2b(fmaxf(sacc[m][2] + b1v.z, 0.f));
                o.w = f2b(fmaxf(sacc[m][3] + b1v.w, 0.f));
                *(ushort4*)&Sbuf[(sidx * 64 + wr * 32 + m * 16 + rl) * 8 + e0] = o;
            }
        }
        LGKM_BARRIER();  // S visible; weight prefetch stays in flight

        // ---- phase B: O += S @ W2c^T (one K=32 step) ----
        {
            bf16x8 sf[2];
#pragma unroll
            for (int m = 0; m < 2; ++m)
                sf[m] = *(const bf16x8*)&Sbuf[ks * 512 + (wr * 32 + m * 16 + rl) * 8];
#pragma unroll
            for (int n = 0; n < 8; ++n) {
                bf16x8 w2f = *(const bf16x8*)&W2buf[ks * 2048 + (wc * 128 + n * 16 + rl) * 8];
#pragma unroll
                for (int m = 0; m < 2; ++m)
                    oacc[m][n] = __builtin_amdgcn_mfma_f32_16x16x32_bf16(sf[m], w2f, oacc[m][n], 0, 0, 0);
            }
        }
        LGKM_BARRIER();  // all LDS reads complete before next overwrite
    }

    float2* lnb = (float2*)W1buf;
    float psum[2][4] = {}, psq[2][4] = {};
#pragma unroll
    for (int n = 0; n < 8; ++n) {
        int c = wc * 128 + n * 16 + rl;
        float bv = b2[c];
#pragma unroll
        for (int m = 0; m < 2; ++m)
#pragma unroll
            for (int r = 0; r < 4; ++r) {
                int grow = row0 + wr * 32 + m * 16 + ks * 4 + r;
                float v = oacc[m][n][r] + bv + b2f(X[(size_t)grow * 256 + c]);
                oacc[m][n][r] = v;
                psum[m][r] += v;
                psq[m][r] = fmaf(v, v, psq[m][r]);
            }
    }
#pragma unroll
    for (int off = 8; off >= 1; off >>= 1)
#pragma unroll
        for (int m = 0; m < 2; ++m)
#pragma unroll
            for (int r = 0; r < 4; ++r) {
                psum[m][r] += __shfl_xor(psum[m][r], off);
                psq[m][r]  += __shfl_xor(psq[m][r], off);
            }
    if (rl == 0) {
#pragma unroll
        for (int m = 0; m < 2; ++m)
#pragma unroll
            for (int r = 0; r < 4; ++r) {
                int lr = wr * 32 + m * 16 + ks * 4 + r;
                lnb[wc * 64 + lr] = make_float2(psum[m][r], psq[m][r]);
            }
    }
    __syncthreads();
    float mean_[2][4], rstd_[2][4];
#pragma unroll
    for (int m = 0; m < 2; ++m)
#pragma unroll
        for (int r = 0; r < 4; ++r) {
            int lr = wr * 32 + m * 16 + ks * 4 + r;
            float2 a0 = lnb[lr], a1 = lnb[64 + lr];
            float mean = (a0.x + a1.x) * (1.f / 256.f);
            float var = (a0.y + a1.y) * (1.f / 256.f) - mean * mean;
            mean_[m][r] = mean;
            rstd_[m][r] = rsqrtf(var + 1e-5f);
        }
#pragma unroll
    for (int n = 0; n < 8; ++n) {
        int c = wc * 128 + n * 16 + rl;
        float gv = g3[c], bev = be3[c];
#pragma unroll
        for (int m = 0; m < 2; ++m)
#pragma unroll
            for (int r = 0; r < 4; ++r) {
                int grow = row0 + wr * 32 + m * 16 + ks * 4 + r;
                if (grow < N)
                    X[(size_t)grow * 256 + c] =
                        f2b((oacc[m][n][r] - mean_[m][r]) * rstd_[m][r] * gv + bev);
            }
    }
}

// ---------------------------------------------------------------------------
// GAT el/er projections, both node sets in one dispatch
// ---------------------------------------------------------------------------
__global__ void attn_lr_all_kernel(
    const ushort* __restrict__ h0, const float* __restrict__ al0, const float* __restrict__ ar0,
    float* __restrict__ el0, float* __restrict__ er0,
    const ushort* __restrict__ h1, const float* __restrict__ al1, const float* __restrict__ ar1,
    float* __restrict__ el1, float* __restrict__ er1)
{
    int idx = blockIdx.x * blockDim.x + threadIdx.x;
    if (idx >= 480000) return;
    const ushort* h; const float *a1, *a2; float *el, *er; int i;
    if (idx < 320000) { h = h0; a1 = al0; a2 = ar0; el = el0; er = er0; i = idx; }
    else { h = h1; a1 = al1; a2 = ar1; el = el1; er = er1; i = idx - 320000; }
    int hd = i & 7;
    const ushort* hp = h + (size_t)(i >> 3) * 256 + hd * 32;
    const float* p1 = a1 + hd * 32;
    const float* p2 = a2 + hd * 32;
    float s1 = 0.f, s2 = 0.f;
#pragma unroll
    for (int j = 0; j < 8; ++j) {
        ushort4 t = ((const ushort4*)hp)[j];
        float v0 = b2f(t.x), v1 = b2f(t.y), v2 = b2f(t.z), v3 = b2f(t.w);
        s1 = fmaf(v0, p1[j * 4 + 0], s1); s2 = fmaf(v0, p2[j * 4 + 0], s2);
        s1 = fmaf(v1, p1[j * 4 + 1], s1); s2 = fmaf(v1, p2[j * 4 + 1], s2);
        s1 = fmaf(v2, p1[j * 4 + 2], s1); s2 = fmaf(v2, p2[j * 4 + 2], s2);
        s1 = fmaf(v3, p1[j * 4 + 3], s1); s2 = fmaf(v3, p2[j * 4 + 3], s2);
    }
    el[i] = s1;
    er[i] = s2;
}

// ---------------------------------------------------------------------------
// CSR build: dual count; 2-stage scan (parts-prefix folded into final); scatter
// ---------------------------------------------------------------------------
__global__ void count2_kernel(const int* __restrict__ d0, int* __restrict__ c0,
                              const int* __restrict__ d1, int* __restrict__ c1, int E)
{
    int e = blockIdx.x * blockDim.x + threadIdx.x;
    if (e < E) atomicAdd(&c0[d0[e]], 1);
    else if (e < 2 * E) atomicAdd(&c1[d1[e - E]], 1);
}

__global__ void scan_chunk_kernel(const int* __restrict__ deg0, int* __restrict__ offs0,
                                  const int* __restrict__ deg1, int* __restrict__ offs1,
                                  int* __restrict__ parts, int N)
{
    int es = blockIdx.x / 20, ch = blockIdx.x % 20;
    const int* deg = es ? deg1 : deg0;
    int* offs = es ? offs1 : offs0;
    __shared__ int sbuf[1024];
    int tid = threadIdx.x;
    int i = ch * 1024 + tid;
    int v = (i < N) ? deg[i] : 0;
    sbuf[tid] = v;
    __syncthreads();
    for (int off = 1; off < 1024; off <<= 1) {
        int t = (tid >= off) ? sbuf[tid - off] : 0;
        __syncthreads();
        sbuf[tid] += t;
        __syncthreads();
    }
    if (i < N) offs[i] = sbuf[tid] - v;
    if (tid == 1023) parts[es * 21 + ch] = sbuf[1023];   // raw chunk total
}

__global__ void scan_final_kernel(int* __restrict__ deg0, int* __restrict__ offs0,
                                  int* __restrict__ deg1, int* __restrict__ offs1,
                                  const int* __restrict__ parts, int N)
{
    int es = blockIdx.x / 20, ch = blockIdx.x % 20;
    int* deg = es ? deg1 : deg0;
    int* offs = es ? offs1 : offs0;
    __shared__ int base_s, tot_s;
    int tid = threadIdx.x;
    if (tid == 0) {
        const int* p = parts + es * 21;
        int acc = 0, base = 0;
        for (int i = 0; i < 20; ++i) { if (i == ch) base = acc; acc += p[i]; }
        base_s = base;
        tot_s = acc;
    }
    __syncthreads();
    int i = ch * 1024 + tid;
    if (i < N) { offs[i] += base_s; deg[i] = 0; }
    if (ch == 19 && tid == 1023) offs[N] = tot_s;
}

__global__ void scatter2_kernel(const int* __restrict__ s0, const int* __restrict__ d0,
                                const int* __restrict__ o0, int* __restrict__ c0, int* __restrict__ l0,
                                const int* __restrict__ s1, const int* __restrict__ d1,
                                const int* __restrict__ o1, int* __restrict__ c1, int* __restrict__ l1,
                                int E)
{
    int e = blockIdx.x * blockDim.x + threadIdx.x;
    if (e < E) {
        int d = d0[e];
        int pos = atomicAdd(&c0[d], 1);
        l0[o0[d] + pos] = s0[e];
    } else if (e < 2 * E) {
        int e1 = e - E;
        int d = d1[e1];
        int pos = atomicAdd(&c1[d], 1);
        l1[o1[d] + pos] = s1[e1];
    }
}

// ---------------------------------------------------------------------------
// GAT aggregation, both edge sets: blocks [0,20000) = ap, [20000,40000) = pp
// ---------------------------------------------------------------------------
__global__ __launch_bounds__(64) void gat_agg_all_kernel(
    const ushort* __restrict__ ha, const float* __restrict__ ela, const float* __restrict__ era,
    const int* __restrict__ offsa, const int* __restrict__ lista, const float* __restrict__ biasa,
    const ushort* __restrict__ hp, const float* __restrict__ elp, const float* __restrict__ erp,
    const int* __restrict__ offsp, const int* __restrict__ listp, const float* __restrict__ biasp,
    ushort* __restrict__ out)
{
    int bid = blockIdx.x;
    const ushort* h; const float *el, *er, *bias; const int *offs, *elist;
    int p, dn, coloff;
    if (bid < NP_N) {
        h = ha; el = ela; er = era; offs = offsa; elist = lista; bias = biasa;
        p = bid; dn = NA_N + p; coloff = 256;
    } else {
        h = hp; el = elp; er = erp; offs = offsp; elist = listp; bias = biasp;
        p = bid - NP_N; dn = p; coloff = 512;
    }
    int l = threadIdx.x;
    int head = l >> 3;
    float erv = er[(size_t)dn * 8 + head];
    float acc[4] = {0.f, 0.f, 0.f, 0.f};
    float z = 0.f;
    int beg = offs[p], end = offs[p + 1];
    for (int e = beg - 1; e < end; ++e) {
        int s = (e < beg) ? dn : elist[e];
        float x = el[(size_t)s * 8 + head] + erv;
        x = x > 0.f ? x : 0.2f * x;
        float wgt = expf(x);
        z += wgt;
        ushort4 hv = *(const ushort4*)&h[(size_t)s * 256 + l * 4];
        acc[0] = fmaf(wgt, b2f(hv.x), acc[0]);
        acc[1] = fmaf(wgt, b2f(hv.y), acc[1]);
        acc[2] = fmaf(wgt, b2f(hv.z), acc[2]);
        acc[3] = fmaf(wgt, b2f(hv.w), acc[3]);
    }
    float inv = 1.f / z;
    ushort4 o;
    o.x = f2b(acc[0] * inv + bias[l * 4 + 0]);
    o.y = f2b(acc[1] * inv + bias[l * 4 + 1]);
    o.z = f2b(acc[2] * inv + bias[l * 4 + 2]);
    o.w = f2b(acc[3] * inv + bias[l * 4 + 3]);
    *(ushort4*)&out[(size_t)p * 768 + coloff + l * 4] = o;
}

// ---------------------------------------------------------------------------
// Tiny MHA (S=Sk=3). Writes output IN-PLACE over the q slice.
// ---------------------------------------------------------------------------
__global__ void mha3_kernel(const ushort* qb, int ldq, int qoff,
                            const ushort* kvb, int ldkv, int koff, int voff,
                            ushort* ob, int ldo, int NPn)
{
    int idx = blockIdx.x * blockDim.x + threadIdx.x;
    if (idx >= NPn * 24) return;
    int h = idx & 7;
    int i = (idx >> 3) % 3;
    int p = idx / 24;
    float qr[32];
    {
        const ushort* q = qb + (size_t)(p * 3 + i) * ldq + qoff + h * 32;
#pragma unroll
        for (int j = 0; j < 8; ++j) {
            ushort4 t = ((const ushort4*)q)[j];
            qr[j * 4 + 0] = b2f(t.x); qr[j * 4 + 1] = b2f(t.y);
            qr[j * 4 + 2] = b2f(t.z); qr[j * 4 + 3] = b2f(t.w);
        }
    }
    float s[3];
#pragma unroll
    for (int j = 0; j < 3; ++j) {
        const ushort* k = kvb + (size_t)(p * 3 + j) * ldkv + koff + h * 32;
        float a = 0.f;
#pragma unroll
        for (int t4 = 0; t4 < 8; ++t4) {
            ushort4 t = ((const ushort4*)k)[t4];
            a = fmaf(qr[t4 * 4 + 0], b2f(t.x), a);
            a = fmaf(qr[t4 * 4 + 1], b2f(t.y), a);
            a = fmaf(qr[t4 * 4 + 2], b2f(t.z), a);
            a = fmaf(qr[t4 * 4 + 3], b2f(t.w), a);
        }
        s[j] = a * 0.17677669529663687f;
    }
    float m = fmaxf(s[0], fmaxf(s[1], s[2]));
    float e0 = expf(s[0] - m), e1 = expf(s[1] - m), e2 = expf(s[2] - m);
    float inv = 1.f / (e0 + e1 + e2);
    float aw[3] = {e0 * inv, e1 * inv, e2 * inv};
    float o[32] = {};
#pragma unroll
    for (int j = 0; j < 3; ++j) {
        const ushort* v = kvb + (size_t)(p * 3 + j) * ldkv + voff + h * 32;
#pragma unroll
        for (int t4 = 0; t4 < 8; ++t4) {
            ushort4 t = ((const ushort4*)v)[t4];
            o[t4 * 4 + 0] = fmaf(aw[j], b2f(t.x), o[t4 * 4 + 0]);
            o[t4 * 4 + 1] = fmaf(aw[j], b2f(t.y), o[t4 * 4 + 1]);
            o[t4 * 4 + 2] = fmaf(aw[j], b2f(t.z), o[t4 * 4 + 2]);
            o[t4 * 4 + 3] = fmaf(aw[j], b2f(t.w), o[t4 * 4 + 3]);
        }
    }
    ushort* op = ob + (size_t)(p * 3 + i) * ldo + h * 32;
#pragma unroll
    for (int t4 = 0; t4 < 8; ++t4) {
        ushort4 t;
        t.x = f2b(o[t4 * 4 + 0]); t.y = f2b(o[t4 * 4 + 1]);
        t.z = f2b(o[t4 * 4 + 2]); t.w = f2b(o[t4 * 4 + 3]);
        ((ushort4*)op)[t4] = t;
    }
}

// ---------------------------------------------------------------------------
// kernel_launch — ws layout (bytes), total 184.32 MB (proven safe):
// [0, 30.72M) tgt_bf | [30.72M, 61.44M) X_bf | [61.44M, 65.28M) packed W
// [65.28M, 184.32M) BIG (era-overlaid)
// ---------------------------------------------------------------------------
extern "C" void kernel_launch(void* const* d_in, const int* in_sizes, int n_in,
                              void* d_out, int out_size, void* d_ws, size_t ws_size,
                              hipStream_t stream)
{
    const float* feat_paper  = (const float*)d_in[0];
    const float* feat_author = (const float*)d_in[1];
    const float* W_in_p  = (const float*)d_in[2];
    const float* b_in_p  = (const float*)d_in[3];
    const float* W_in_a  = (const float*)d_in[4];
    const float* b_in_a  = (const float*)d_in[5];
    const float* W_gat_ap = (const float*)d_in[6];
    const float* al_ap    = (const float*)d_in[7];
    const float* ar_ap    = (const float*)d_in[8];
    const float* b_gat_ap = (const float*)d_in[9];
    const float* W_gat_pp = (const float*)d_in[10];
    const float* al_pp    = (const float*)d_in[11];
    const float* ar_pp    = (const float*)d_in[12];
    const float* b_gat_pp = (const float*)d_in[13];
    const float* Wqkv_s = (const float*)d_in[14];
    const float* bqkv_s = (const float*)d_in[15];
    const float* Wo_s   = (const float*)d_in[16];
    const float* bo_s   = (const float*)d_in[17];
    const float* Wqkv_c = (const float*)d_in[18];
    const float* bqkv_c = (const float*)d_in[19];
    const float* Wo_c   = (const float*)d_in[20];
    const float* bo_c   = (const float*)d_in[21];
    const float* W_ff1  = (const float*)d_in[22];
    const float* b_ff1  = (const float*)d_in[23];
    const float* W_ff2  = (const float*)d_in[24];
    const float* b_ff2  = (const float*)d_in[25];
    const float* ln1_g  = (const float*)d_in[26];
    const float* ln1_b  = (const float*)d_in[27];
    const float* ln2_g  = (const float*)d_in[28];
    const float* ln2_b  = (const float*)d_in[29];
    const float* ln3_g  = (const float*)d_in[30];
    const float* ln3_b  = (const float*)d_in[31];
    const float* W_pred = (const float*)d_in[32];
    const float* b_pred = (const float*)d_in[33];
    const int* ap_src = (const int*)d_in[34];
    const int* ap_dst = (const int*)d_in[35];
    const int* pp_src = (const int*)d_in[36];
    const int* pp_dst = (const int*)d_in[37];

    const int NP = NP_N, NA = NA_N;

    uint8_t* wsb = (uint8_t*)d_ws;
    ushort* tgt_bf = (ushort*)wsb;
    ushort* X_bf   = (ushort*)(wsb + 30720000);
    ushort* WB     = (ushort*)(wsb + 61440000);
    ushort* p_in_p   = WB + 0;
    ushort* p_in_a   = WB + 32768;
    ushort* p_gat_ap = WB + 65536;
    ushort* p_gat_pp = WB + 131072;
    ushort* p_qkv_s  = WB + 196608;
    ushort* p_o_s    = WB + 393216;
    ushort* p_qkv_c  = WB + 458752;
    ushort* p_o_c    = WB + 655360;
    ushort* p_pred   = WB + 720896;
    ushort* p_ff1    = WB + 819200;
    ushort* p_ff2    = WB + 1343488;
    uint8_t* BIG = wsb + 65280000;

    // era A overlay inside BIG (hp lives directly in tgt slot 0)
    ushort* feat_p_bf = (ushort*)BIG;
    ushort* feat_a_bf = (ushort*)(BIG + 5120000);
    ushort* x_ap_bf   = (ushort*)(BIG + 10240000);   // authors only (20000,256)
    ushort* h_ap_bf   = (ushort*)(BIG + 30720000);
    ushort* h_pp_bf   = (ushort*)(BIG + 51200000);
    float* el_ap = (float*)(BIG + 61440000);
    float* er_ap = (float*)(BIG + 62720000);
    float* el_pp = (float*)(BIG + 64000000);
    float* er_pp = (float*)(BIG + 64640000);
    int* ireg    = (int*)(BIG + 65280000);
    int* ap_offs = ireg;
    int* pp_offs = ireg + 20004;
    int* ap_cur  = ireg + 40008;
    int* pp_cur  = ireg + 60008;
    int* ap_list = ireg + 80008;
    int* pp_list = ireg + 480008;
    int* parts   = ireg + 880008;   // [2][21]

    // ---- mega pack: converts + weight packs + counter zero, ONE dispatch ----
    {
        PackJobs J;
        const float* srcs[NJOBS] = { feat_paper, feat_author, W_in_p, W_in_a, W_gat_ap,
                                     W_gat_pp, Wqkv_s, Wo_s, Wqkv_c, Wo_c, W_pred,
                                     W_ff1, W_ff2, nullptr };
        void* dsts[NJOBS] = { feat_p_bf, feat_a_bf, p_in_p, p_in_a, p_gat_ap,
                              p_gat_pp, p_qkv_s, p_o_s, p_qkv_c, p_o_c, p_pred,
                              p_ff1, p_ff2, ap_cur };
        int Ms[NJOBS]  = {0,0, 256,256,256,256, 768,256,768,256, 64, 0,0, 0};
        int Ks[NJOBS]  = {0,0, 128,128,256,256, 256,256,256,256, 768, 0,0, 0};
        int tys[NJOBS] = {3,3, 0,0,0,0, 0,0,0,0, 0, 1,2, 4};
        int nq[NJOBS]  = {640000,640000, 8192,8192,16384,16384, 49152,16384,49152,16384,
                          24576, 131072,131072, 10000};
        int acc = 0;
        for (int j = 0; j < NJOBS; ++j) {
            J.src[j] = srcs[j]; J.dst[j] = dsts[j];
            J.M[j] = Ms[j]; J.K[j] = Ks[j]; J.type[j] = tys[j]; J.nquad[j] = nq[j];
            J.blk0[j] = acc;
            acc += (nq[j] + 255) / 256;
        }
        pack_all_kernel<<<acc, 256, 0, stream>>>(J);
    }

    // ---- batch 1: input projections (authors -> x_ap; papers -> tgt[:,0,:]) ----
    {
        GemmJobs G;
        G.njobs = 2;
        G.A[0] = feat_a_bf; G.Bp[0] = p_in_a; G.bias[0] = b_in_a; G.C[0] = x_ap_bf;
        G.N[0] = NA; G.M[0] = 256; G.K[0] = 128; G.lda[0] = 128; G.ldc[0] = 256;
        G.A[1] = feat_p_bf; G.Bp[1] = p_in_p; G.bias[1] = b_in_p; G.C[1] = tgt_bf;
        G.N[1] = NP; G.M[1] = 256; G.K[1] = 128; G.lda[1] = 128; G.ldc[1] = 768;
        int acc = 0;
        for (int j = 0; j < 2; ++j) {
            G.nbx[j] = (G.N[j] + 127) / 128;
            G.blk0[j] = acc;
            acc += G.nbx[j] * ((G.M[j] + 127) / 128);
        }
        gemm_batch_kernel<<<acc, 256, 0, stream>>>(G);
    }

    // ---- batch 2: GAT feature transforms (3 independent GEMMs) ----
    {
        GemmJobs G;
        G.njobs = 3;
        G.A[0] = x_ap_bf; G.Bp[0] = p_gat_ap; G.bias[0] = nullptr; G.C[0] = h_ap_bf;
        G.N[0] = NA; G.M[0] = 256; G.K[0] = 256; G.lda[0] = 256; G.ldc[0] = 256;
        G.A[1] = tgt_bf; G.Bp[1] = p_gat_ap; G.bias[1] = nullptr; G.C[1] = h_ap_bf + (size_t)NA * 256;
        G.N[1] = NP; G.M[1] = 256; G.K[1] = 256; G.lda[1] = 768; G.ldc[1] = 256;
        G.A[2] = tgt_bf; G.Bp[2] = p_gat_pp; G.bias[2] = nullptr; G.C[2] = h_pp_bf;
        G.N[2] = NP; G.M[2] = 256; G.K[2] = 256; G.lda[2] = 768; G.ldc[2] = 256;
        int acc = 0;
        for (int j = 0; j < 3; ++j) {
            G.nbx[j] = (G.N[j] + 127) / 128;
            G.blk0[j] = acc;
            acc += G.nbx[j] * ((G.M[j] + 127) / 128);
        }
        gemm_batch_kernel<<<acc, 256, 0, stream>>>(G);
    }

    // ---- el/er (one dispatch) ----
    attn_lr_all_kernel<<<1875, 256, 0, stream>>>(h_ap_bf, al_ap, ar_ap, el_ap, er_ap,
                                                 h_pp_bf, al_pp, ar_pp, el_pp, er_pp);

    // ---- CSR build (4 dispatches) ----
    count2_kernel<<<3125, 256, 0, stream>>>(ap_dst, ap_cur, pp_dst, pp_cur, E_AP_N);
    scan_chunk_kernel<<<40, 1024, 0, stream>>>(ap_cur, ap_offs, pp_cur, pp_offs, parts, NP);
    scan_final_kernel<<<40, 1024, 0, stream>>>(ap_cur, ap_offs, pp_cur, pp_offs, parts, NP);
    scatter2_kernel<<<3125, 256, 0, stream>>>(ap_src, ap_dst, ap_offs, ap_cur, ap_list,
                                              pp_src, pp_dst, pp_offs, pp_cur, pp_list, E_AP_N);

    // ---- GAT aggregation (one dispatch) ----
    gat_agg_all_kernel<<<2 * NP, 64, 0, stream>>>(
        h_ap_bf, el_ap, er_ap, ap_offs, ap_list, b_gat_ap,
        h_pp_bf, el_pp, er_pp, pp_offs, pp_list, b_gat_pp, tgt_bf);

    // ---- self attention, full 60000 rows ----
    {
        ushort* qkv = (ushort*)BIG;  // 92.16 MB
        gemm_bf(tgt_bf, p_qkv_s, bqkv_s, qkv, 60000, 768, 256, 256, 768, 0, stream);
        mha3_kernel<<<(NP * 24 + 255) / 256, 256, 0, stream>>>(qkv, 768, 0, qkv, 768, 256, 512, qkv, 768, NP);
        proj_ln_kernel<<<(60000 + 63) / 64, 256, 0, stream>>>(
            qkv, 768, p_o_s, bo_s, tgt_bf, 256, ln1_g, ln1_b, X_bf, 60000);
    }

    // ---- cross attention, full 60000 rows (q + kv batched) ----
    {
        ushort* qb  = (ushort*)BIG;                 // 30.72 MB
        ushort* kvb = (ushort*)(BIG + 30720000);    // 61.44 MB
        const ushort* p_kv_c = p_qkv_c + (size_t)2 * 8 * 4096;  // row-tiles 2..5
        GemmJobs G;
        G.njobs = 2;
        G.A[0] = X_bf; G.Bp[0] = p_qkv_c; G.bias[0] = bqkv_c; G.C[0] = qb;
        G.N[0] = 60000; G.M[0] = 256; G.K[0] = 256; G.lda[0] = 256; G.ldc[0] = 256;
        G.A[1] = tgt_bf; G.Bp[1] = p_kv_c; G.bias[1] = bqkv_c + 256; G.C[1] = kvb;
        G.N[1] = 60000; G.M[1] = 512; G.K[1] = 256; G.lda[1] = 256; G.ldc[1] = 512;
        int acc = 0;
        for (int j = 0; j < 2; ++j) {
            G.nbx[j] = (G.N[j] + 127) / 128;
            G.blk0[j] = acc;
            acc += G.nbx[j] * ((G.M[j] + 127) / 128);
        }
        gemm_batch_kernel<<<acc, 256, 0, stream>>>(G);
        mha3_kernel<<<(NP * 24 + 255) / 256, 256, 0, stream>>>(qb, 256, 0, kvb, 512, 0, 256, qb, 256, NP);
        proj_ln_kernel<<<(60000 + 63) / 64, 256, 0, stream>>>(
            qb, 256, p_o_c, bo_c, X_bf, 256, ln2_g, ln2_b, X_bf, 60000);
    }

    // ---- feed-forward + residual + LN3 fused (v9, async-stage), X in place ----
    ff_ln_kernel<<<(60000 + 63) / 64, 256, 0, stream>>>(p_ff1, p_ff2, b_ff1, b_ff2,
                                                        ln3_g, ln3_b, X_bf, 60000);

    // ---- prediction head ----
    gemm_bf(X_bf, p_pred, b_pred, (float*)d_out, NP, 64, 768, 768, 64, 1, stream);
}

// Round 21
// 746.865 us; speedup vs baseline: 1.0097x; 1.0097x over previous
//
#include <hip/hip_runtime.h>
#include <hip/hip_bf16.h>
#include <cstdint>
#include <cstddef>

#define NP_N 20000
#define NA_N 20000
#define E_AP_N 400000
#define E_PP_N 400000
// D_IN=128, D_H=256, HEADS=8, D_HEAD=32, D_FF=2048, D_OUT=64

typedef __attribute__((ext_vector_type(8))) short bf16x8;
typedef __attribute__((ext_vector_type(4))) float f32x4;

__device__ __forceinline__ float b2f(ushort u) { return __uint_as_float(((uint32_t)u) << 16); }
__device__ __forceinline__ ushort f2b(float f) {
    uint32_t x = __float_as_uint(f);
    return (ushort)((x + 0x7fffu + ((x >> 16) & 1u)) >> 16);  // RNE (no NaN inputs here)
}

#define LGKM_BARRIER() do { \
    asm volatile("s_waitcnt lgkmcnt(0)" ::: "memory"); \
    __builtin_amdgcn_s_barrier(); \
    __builtin_amdgcn_sched_barrier(0); \
} while (0)

// ---------------------------------------------------------------------------
// Mega pack kernel (converts + weight packs + counter zero), one dispatch.
// types: 0=packB gemm order, 1=packW1 ff, 2=packW2 ff, 3=cvt, 4=zero int4
// ---------------------------------------------------------------------------
#define NJOBS 14
struct PackJobs {
    const float* src[NJOBS];
    void* dst[NJOBS];
    int M[NJOBS], K[NJOBS];
    int type[NJOBS];
    int nquad[NJOBS];
    int blk0[NJOBS];
};

__global__ void pack_all_kernel(PackJobs J)
{
    int b = blockIdx.x;
    int j = 0;
    while (j + 1 < NJOBS && b >= J.blk0[j + 1]) ++j;
    int u = (b - J.blk0[j]) * 256 + threadIdx.x;
    if (u >= J.nquad[j]) return;
    int ty = J.type[j];
    const float* src = J.src[j];
    if (ty == 3) {
        float4 v = ((const float4*)src)[u];
        ushort4 o;
        o.x = f2b(v.x); o.y = f2b(v.y); o.z = f2b(v.z); o.w = f2b(v.w);
        ((ushort4*)J.dst[j])[u] = o;
    } else if (ty == 4) {
        int4 z = {0, 0, 0, 0};
        ((int4*)J.dst[j])[u] = z;
    } else if (ty == 0) {
        // out[(jt*KT+t)*4096 + ks*1024 + r*8 + e] = B[jt*128+r][t*32+ks*8+e]
        int M = J.M[j], K = J.K[j];
        int KT = K >> 5;
        int q = u & 1023;
        int jt = u >> 10;
        int t = jt % KT, jj = jt / KT;
        int ks = q >> 8, rem = q & 255;
        int r = rem >> 1;
        int e0 = (rem & 1) * 4;
        int row = jj * 128 + r;
        ushort4 o = {0, 0, 0, 0};
        if (row < M) {
            const float* s = src + (size_t)row * K + t * 32 + ks * 8 + e0;
            o.x = f2b(s[0]); o.y = f2b(s[1]); o.z = f2b(s[2]); o.w = f2b(s[3]);
        }
        ((ushort4*)J.dst[j])[u] = o;
    } else if (ty == 1) {
        // W1(2048,256) -> [chunk32f][s32][f32][8]
        int q = u & 2047, chunk = u >> 11;
        int s = q >> 6, rem = q & 63;
        int fl = rem >> 1, e0 = (rem & 1) * 4;
        const float* sp = src + (size_t)(chunk * 32 + fl) * 256 + s * 8 + e0;
        ushort4 o;
        o.x = f2b(sp[0]); o.y = f2b(sp[1]); o.z = f2b(sp[2]); o.w = f2b(sp[3]);
        ((ushort4*)J.dst[j])[u] = o;
    } else {
        // W2(256,2048) -> [chunk32f][s2 4][c256][8]
        int q = u & 2047, chunk = u >> 11;
        int s2 = q >> 9, rem = q & 511;
        int c = rem >> 1, e0 = (rem & 1) * 4;
        const float* sp = src + (size_t)c * 2048 + chunk * 32 + s2 * 8 + e0;
        ushort4 o;
        o.x = f2b(sp[0]); o.y = f2b(sp[1]); o.z = f2b(sp[2]); o.w = f2b(sp[3]);
        ((ushort4*)J.dst[j])[u] = o;
    }
}

// ---------------------------------------------------------------------------
// Shared GEMM K-loop body (bf16 out): C(N,M)=A(N,K)@Bp^T+bias at (row0,col0).
// ---------------------------------------------------------------------------
__device__ __forceinline__ void gemm_body_bf16(
    ushort* Ab, ushort* Bb,   // LDS: 3*4096 each
    const ushort* A, const ushort* Bp, const float* bias, ushort* C,
    int N, int M, int K, int lda, int ldc, int row0, int col0)
{
    const int tid = threadIdx.x;
    const int lane = tid & 63;
    const int w = tid >> 6;
    const int wr = w >> 1, wc = w & 1;
    const int KT = K >> 5;
    const ushort* Bbase = Bp + (size_t)(col0 >> 7) * KT * 4096;
    f32x4 acc[4][4] = {};

    size_t aoff[2];
#pragma unroll
    for (int i = 0; i < 2; ++i) {
        int r = row0 + i * 64 + lane;
        if (r > N - 1) r = N - 1;
        aoff[i] = (size_t)r * lda + w * 8;
    }

    auto stage = [&](int buf, int t) {
        const int k0 = t << 5;
#pragma unroll
        for (int i = 0; i < 2; ++i) {
            __builtin_amdgcn_global_load_lds(
                (const __attribute__((address_space(1))) void*)(A + aoff[i] + k0),
                (__attribute__((address_space(3))) void*)(&Ab[buf * 4096 + (w * 2 + i) * 512]), 16, 0, 0);
        }
#pragma unroll
        for (int i = 0; i < 2; ++i) {
            __builtin_amdgcn_global_load_lds(
                (const __attribute__((address_space(1))) void*)(Bbase + (size_t)t * 4096 + (w * 2 + i) * 512 + lane * 8),
                (__attribute__((address_space(3))) void*)(&Bb[buf * 4096 + (w * 2 + i) * 512]), 16, 0, 0);
        }
    };

    stage(0, 0);
    stage(1, 1);

    int cur = 0;
    for (int t = 0; t < KT; ++t) {
        if (t + 1 < KT) { asm volatile("s_waitcnt vmcnt(4)" ::: "memory"); }
        else            { asm volatile("s_waitcnt vmcnt(0)" ::: "memory"); }
        __builtin_amdgcn_s_barrier();
        __builtin_amdgcn_sched_barrier(0);
        if (t + 2 < KT) {
            int nb = cur - 1; if (nb < 0) nb = 2;   // (t+2)%3
            stage(nb, t + 2);
        }

        bf16x8 af[4], bfr[4];
        const int ks = lane >> 4;
        const int rl = lane & 15;
#pragma unroll
        for (int m = 0; m < 4; ++m)
            af[m] = *(const bf16x8*)&Ab[cur * 4096 + ks * 1024 + (wr * 64 + m * 16 + rl) * 8];
#pragma unroll
        for (int n = 0; n < 4; ++n)
            bfr[n] = *(const bf16x8*)&Bb[cur * 4096 + ks * 1024 + (wc * 64 + n * 16 + rl) * 8];
#pragma unroll
        for (int m = 0; m < 4; ++m)
#pragma unroll
            for (int n = 0; n < 4; ++n)
                acc[m][n] = __builtin_amdgcn_mfma_f32_16x16x32_bf16(af[m], bfr[n], acc[m][n], 0, 0, 0);

        cur = (cur == 2) ? 0 : cur + 1;
    }

#pragma unroll
    for (int m = 0; m < 4; ++m) {
#pragma unroll
        for (int n = 0; n < 4; ++n) {
            int gc = col0 + wc * 64 + n * 16 + (lane & 15);
            if (gc >= M) continue;
            float bv = bias ? bias[gc] : 0.f;
#pragma unroll
            for (int r = 0; r < 4; ++r) {
                int grow = row0 + wr * 64 + m * 16 + (lane >> 4) * 4 + r;
                if (grow >= N) continue;
                C[(size_t)grow * ldc + gc] = f2b(acc[m][n][r] + bv);
            }
        }
    }
}

// ---------------------------------------------------------------------------
// Single GEMM (bf16 or f32 out) — used for qkv_s and prediction head.
// OUT_MODE: 0 = bf16, 1 = f32
// ---------------------------------------------------------------------------
template <int OUT_MODE>
__global__ __launch_bounds__(256) void gemm_mfma(
    const ushort* __restrict__ A, const ushort* __restrict__ Bp,
    const float* __restrict__ bias, void* __restrict__ Cv,
    int N, int M, int K, int lda, int ldc)
{
    __shared__ __align__(16) ushort Ab[3 * 4096];
    __shared__ __align__(16) ushort Bb[3 * 4096];
    if (OUT_MODE == 0) {
        gemm_body_bf16(Ab, Bb, A, Bp, bias, (ushort*)Cv, N, M, K, lda, ldc,
                       blockIdx.x * 128, blockIdx.y * 128);
        return;
    }
    // f32-out path (pred head), same loop
    const int tid = threadIdx.x;
    const int lane = tid & 63;
    const int w = tid >> 6;
    const int wr = w >> 1, wc = w & 1;
    const int row0 = blockIdx.x * 128;
    const int col0 = blockIdx.y * 128;
    const int KT = K >> 5;
    const ushort* Bbase = Bp + (size_t)blockIdx.y * KT * 4096;
    f32x4 acc[4][4] = {};

    size_t aoff[2];
#pragma unroll
    for (int i = 0; i < 2; ++i) {
        int r = row0 + i * 64 + lane;
        if (r > N - 1) r = N - 1;
        aoff[i] = (size_t)r * lda + w * 8;
    }

    auto stage = [&](int buf, int t) {
        const int k0 = t << 5;
#pragma unroll
        for (int i = 0; i < 2; ++i) {
            __builtin_amdgcn_global_load_lds(
                (const __attribute__((address_space(1))) void*)(A + aoff[i] + k0),
                (__attribute__((address_space(3))) void*)(&Ab[buf * 4096 + (w * 2 + i) * 512]), 16, 0, 0);
        }
#pragma unroll
        for (int i = 0; i < 2; ++i) {
            __builtin_amdgcn_global_load_lds(
                (const __attribute__((address_space(1))) void*)(Bbase + (size_t)t * 4096 + (w * 2 + i) * 512 + lane * 8),
                (__attribute__((address_space(3))) void*)(&Bb[buf * 4096 + (w * 2 + i) * 512]), 16, 0, 0);
        }
    };

    stage(0, 0);
    stage(1, 1);

    int cur = 0;
    for (int t = 0; t < KT; ++t) {
        if (t + 1 < KT) { asm volatile("s_waitcnt vmcnt(4)" ::: "memory"); }
        else            { asm volatile("s_waitcnt vmcnt(0)" ::: "memory"); }
        __builtin_amdgcn_s_barrier();
        __builtin_amdgcn_sched_barrier(0);
        if (t + 2 < KT) {
            int nb = cur - 1; if (nb < 0) nb = 2;
            stage(nb, t + 2);
        }

        bf16x8 af[4], bfr[4];
        const int ks = lane >> 4;
        const int rl = lane & 15;
#pragma unroll
        for (int m = 0; m < 4; ++m)
            af[m] = *(const bf16x8*)&Ab[cur * 4096 + ks * 1024 + (wr * 64 + m * 16 + rl) * 8];
#pragma unroll
        for (int n = 0; n < 4; ++n)
            bfr[n] = *(const bf16x8*)&Bb[cur * 4096 + ks * 1024 + (wc * 64 + n * 16 + rl) * 8];
#pragma unroll
        for (int m = 0; m < 4; ++m)
#pragma unroll
            for (int n = 0; n < 4; ++n)
                acc[m][n] = __builtin_amdgcn_mfma_f32_16x16x32_bf16(af[m], bfr[n], acc[m][n], 0, 0, 0);

        cur = (cur == 2) ? 0 : cur + 1;
    }

#pragma unroll
    for (int m = 0; m < 4; ++m) {
#pragma unroll
        for (int n = 0; n < 4; ++n) {
            int gc = col0 + wc * 64 + n * 16 + (lane & 15);
            if (gc >= M) continue;
            float bv = bias ? bias[gc] : 0.f;
#pragma unroll
            for (int r = 0; r < 4; ++r) {
                int grow = row0 + wr * 64 + m * 16 + (lane >> 4) * 4 + r;
                if (grow >= N) continue;
                ((float*)Cv)[(size_t)grow * ldc + gc] = acc[m][n][r] + bv;
            }
        }
    }
}

static inline void gemm_bf(const ushort* A, const ushort* Bp, const float* bias, void* C,
                           int N, int M, int K, int lda, int ldc, int mode, hipStream_t s)
{
    dim3 g((N + 127) / 128, (M + 127) / 128);
    if (mode == 0) gemm_mfma<0><<<g, 256, 0, s>>>(A, Bp, bias, C, N, M, K, lda, ldc);
    else           gemm_mfma<1><<<g, 256, 0, s>>>(A, Bp, bias, C, N, M, K, lda, ldc);
}

// ---------------------------------------------------------------------------
// Batched GEMM: up to 3 independent bf16-out GEMMs in one dispatch.
// ---------------------------------------------------------------------------
#define GNJ 3
struct GemmJobs {
    const ushort* A[GNJ];
    const ushort* Bp[GNJ];
    const float* bias[GNJ];
    ushort* C[GNJ];
    int N[GNJ], M[GNJ], K[GNJ], lda[GNJ], ldc[GNJ];
    int blk0[GNJ], nbx[GNJ];
    int njobs;
};

__global__ __launch_bounds__(256) void gemm_batch_kernel(GemmJobs G)
{
    __shared__ __align__(16) ushort Ab[3 * 4096];
    __shared__ __align__(16) ushort Bb[3 * 4096];
    int b = blockIdx.x;
    int j = 0;
    while (j + 1 < G.njobs && b >= G.blk0[j + 1]) ++j;
    int lb = b - G.blk0[j];
    int bx = lb % G.nbx[j];
    int by = lb / G.nbx[j];
    gemm_body_bf16(Ab, Bb, G.A[j], G.Bp[j], G.bias[j], G.C[j],
                   G.N[j], G.M[j], G.K[j], G.lda[j], G.ldc[j], bx * 128, by * 128);
}

// ---------------------------------------------------------------------------
// Fused o-proj + residual + LayerNorm:  X <- LayerNorm(res + o @ Wo^T + bo)
// ---------------------------------------------------------------------------
__global__ __launch_bounds__(256, 2) void proj_ln_kernel(
    const ushort* o, int ldo,
    const ushort* __restrict__ Bp, const float* __restrict__ bo,
    const ushort* res, int ldr,
    const float* __restrict__ g, const float* __restrict__ be,
    ushort* X, int N)
{
    __shared__ __align__(16) ushort Wb[8192];   // [tile2][ks4][r128][8] 16KB
    const int tid = threadIdx.x;
    const int lane = tid & 63;
    const int w = tid >> 6;
    const int wr = w >> 1, wc = w & 1;
    const int row0 = blockIdx.x * 64;
    const int rl = lane & 15;
    const int ks = lane >> 4;

    int arow[2];
#pragma unroll
    for (int m = 0; m < 2; ++m) {
        int r = row0 + wr * 32 + m * 16 + rl;
        arow[m] = (r < N) ? r : (N - 1);
    }

    f32x4 oacc[2][8] = {};

    for (int t = 0; t < 8; ++t) {
#pragma unroll
        for (int i = 0; i < 4; ++i) {
            int ii = w * 4 + i;   // 0..15
            const ushort* src = Bp + ((size_t)(ii >> 3) * 8 + t) * 4096 + (ii & 7) * 512 + lane * 8;
            __builtin_amdgcn_global_load_lds(
                (const __attribute__((address_space(1))) void*)src,
                (__attribute__((address_space(3))) void*)(&Wb[ii * 512]), 16, 0, 0);
        }
        bf16x8 af[2];
#pragma unroll
        for (int m = 0; m < 2; ++m)
            af[m] = *(const bf16x8*)(o + (size_t)arow[m] * ldo + t * 32 + ks * 8);
        __syncthreads();

#pragma unroll
        for (int n = 0; n < 8; ++n) {
            bf16x8 bfr = *(const bf16x8*)&Wb[wc * 4096 + ks * 1024 + (n * 16 + rl) * 8];
#pragma unroll
            for (int m = 0; m < 2; ++m)
                oacc[m][n] = __builtin_amdgcn_mfma_f32_16x16x32_bf16(af[m], bfr, oacc[m][n], 0, 0, 0);
        }
        __syncthreads();
    }

    float2* lnb = (float2*)Wb;
    float psum[2][4] = {}, psq[2][4] = {};
#pragma unroll
    for (int n = 0; n < 8; ++n) {
        int c = wc * 128 + n * 16 + rl;
        float bv = bo[c];
#pragma unroll
        for (int m = 0; m < 2; ++m)
#pragma unroll
            for (int r = 0; r < 4; ++r) {
                int grow = row0 + wr * 32 + m * 16 + ks * 4 + r;
                float v = oacc[m][n][r] + bv + b2f(res[(size_t)grow * ldr + c]);
                oacc[m][n][r] = v;
                psum[m][r] += v;
                psq[m][r] = fmaf(v, v, psq[m][r]);
            }
    }
#pragma unroll
    for (int off = 8; off >= 1; off >>= 1)
#pragma unroll
        for (int m = 0; m < 2; ++m)
#pragma unroll
            for (int r = 0; r < 4; ++r) {
                psum[m][r] += __shfl_xor(psum[m][r], off);
                psq[m][r]  += __shfl_xor(psq[m][r], off);
            }
    if (rl == 0) {
#pragma unroll
        for (int m = 0; m < 2; ++m)
#pragma unroll
            for (int r = 0; r < 4; ++r) {
                int lr = wr * 32 + m * 16 + ks * 4 + r;
                lnb[wc * 64 + lr] = make_float2(psum[m][r], psq[m][r]);
            }
    }
    __syncthreads();
    float mean_[2][4], rstd_[2][4];
#pragma unroll
    for (int m = 0; m < 2; ++m)
#pragma unroll
        for (int r = 0; r < 4; ++r) {
            int lr = wr * 32 + m * 16 + ks * 4 + r;
            float2 a0 = lnb[lr], a1 = lnb[64 + lr];
            float mean = (a0.x + a1.x) * (1.f / 256.f);
            float var = (a0.y + a1.y) * (1.f / 256.f) - mean * mean;
            mean_[m][r] = mean;
            rstd_[m][r] = rsqrtf(var + 1e-5f);
        }
#pragma unroll
    for (int n = 0; n < 8; ++n) {
        int c = wc * 128 + n * 16 + rl;
        float gv = g[c], bev = be[c];
#pragma unroll
        for (int m = 0; m < 2; ++m)
#pragma unroll
            for (int r = 0; r < 4; ++r) {
                int grow = row0 + wr * 32 + m * 16 + ks * 4 + r;
                if (grow < N)
                    X[(size_t)grow * 256 + c] =
                        f2b((oacc[m][n][r] - mean_[m][r]) * rstd_[m][r] * gv + bev);
            }
    }
}

// ---------------------------------------------------------------------------
// Fused FF + residual + LN3 v8 (measured optimum):
//   X <- LayerNorm(X + relu(X@W1^T+b1)@W2^T + b2)   [in place]
// 64 rows/block, 256 thr, single-buffered gload_lds staging, draining barriers.
// ---------------------------------------------------------------------------
__global__ __launch_bounds__(256, 2) void ff_ln_kernel(
    const ushort* __restrict__ W1p, const ushort* __restrict__ W2p,
    const float* __restrict__ b1, const float* __restrict__ b2,
    const float* __restrict__ g3, const float* __restrict__ be3,
    ushort* X, int N)
{
    __shared__ __align__(16) ushort W1buf[8192];  // [s32][f32][8]   16KB
    __shared__ __align__(16) ushort W2buf[8192];  // [s2 4][c256][8] 16KB
    __shared__ __align__(16) ushort Sbuf[2048];   // [s 4][row64][8]  4KB
    const int tid = threadIdx.x;
    const int lane = tid & 63;
    const int w = tid >> 6;
    const int wr = w >> 1, wc = w & 1;
    const int row0 = blockIdx.x * 64;
    const int rl = lane & 15;
    const int ks = lane >> 4;

    bf16x8 xf[2][8];
#pragma unroll
    for (int m = 0; m < 2; ++m) {
        int gr = row0 + wr * 32 + m * 16 + rl;
        if (gr > N - 1) gr = N - 1;
        const ushort* xrow = X + (size_t)gr * 256 + ks * 8;
#pragma unroll
        for (int kc = 0; kc < 8; ++kc)
            xf[m][kc] = *(const bf16x8*)(xrow + kc * 32);
    }

    f32x4 oacc[2][8] = {};

    for (int fc = 0; fc < 64; ++fc) {
#pragma unroll
        for (int i = 0; i < 8; ++i) {
            int ii = w * 8 + i;
            const ushort* src;
            ushort* dst;
            if (ii < 16) {
                src = W1p + (size_t)fc * 8192 + ii * 512 + lane * 8;
                dst = &W1buf[ii * 512];
            } else {
                src = W2p + (size_t)fc * 8192 + (ii - 16) * 512 + lane * 8;
                dst = &W2buf[(ii - 16) * 512];
            }
            __builtin_amdgcn_global_load_lds(
                (const __attribute__((address_space(1))) void*)src,
                (__attribute__((address_space(3))) void*)dst, 16, 0, 0);
        }
        __syncthreads();

        f32x4 sacc[2] = {};
#pragma unroll
        for (int kc = 0; kc < 8; ++kc) {
            bf16x8 w1f = *(const bf16x8*)&W1buf[(kc * 4 + ks) * 256 + (wc * 16 + rl) * 8];
#pragma unroll
            for (int m = 0; m < 2; ++m)
                sacc[m] = __builtin_amdgcn_mfma_f32_16x16x32_bf16(w1f, xf[m][kc], sacc[m], 0, 0, 0);
        }
        {
            const int f0 = fc * 32;
            const int fb = wc * 16 + ks * 4;
            const int sidx = wc * 2 + (ks >> 1);
            const int e0 = (ks & 1) * 4;
            float4 b1v = *(const float4*)&b1[f0 + fb];
#pragma unroll
            for (int m = 0; m < 2; ++m) {
                ushort4 o;
                o.x = f2b(fmaxf(sacc[m][0] + b1v.x, 0.f));
                o.y = f2b(fmaxf(sacc[m][1] + b1v.y, 0.f));
                o.z = f2b(fmaxf(sacc[m][2] + b1v.z, 0.f));
                o.w = f2b(fmaxf(sacc[m][3] + b1v.w, 0.f));
                *(ushort4*)&Sbuf[(sidx * 64 + wr * 32 + m * 16 + rl) * 8 + e0] = o;
            }
        }
        LGKM_BARRIER();

        {
            bf16x8 sf[2];
#pragma unroll
            for (int m = 0; m < 2; ++m)
                sf[m] = *(const bf16x8*)&Sbuf[ks * 512 + (wr * 32 + m * 16 + rl) * 8];
#pragma unroll
            for (int n = 0; n < 8; ++n) {
                bf16x8 w2f = *(const bf16x8*)&W2buf[ks * 2048 + (wc * 128 + n * 16 + rl) * 8];
#pragma unroll
                for (int m = 0; m < 2; ++m)
                    oacc[m][n] = __builtin_amdgcn_mfma_f32_16x16x32_bf16(sf[m], w2f, oacc[m][n], 0, 0, 0);
            }
        }
        __syncthreads();
    }

    float2* lnb = (float2*)W1buf;
    float psum[2][4] = {}, psq[2][4] = {};
#pragma unroll
    for (int n = 0; n < 8; ++n) {
        int c = wc * 128 + n * 16 + rl;
        float bv = b2[c];
#pragma unroll
        for (int m = 0; m < 2; ++m)
#pragma unroll
            for (int r = 0; r < 4; ++r) {
                int grow = row0 + wr * 32 + m * 16 + ks * 4 + r;
                float v = oacc[m][n][r] + bv + b2f(X[(size_t)grow * 256 + c]);
                oacc[m][n][r] = v;
                psum[m][r] += v;
                psq[m][r] = fmaf(v, v, psq[m][r]);
            }
    }
#pragma unroll
    for (int off = 8; off >= 1; off >>= 1)
#pragma unroll
        for (int m = 0; m < 2; ++m)
#pragma unroll
            for (int r = 0; r < 4; ++r) {
                psum[m][r] += __shfl_xor(psum[m][r], off);
                psq[m][r]  += __shfl_xor(psq[m][r], off);
            }
    if (rl == 0) {
#pragma unroll
        for (int m = 0; m < 2; ++m)
#pragma unroll
            for (int r = 0; r < 4; ++r) {
                int lr = wr * 32 + m * 16 + ks * 4 + r;
                lnb[wc * 64 + lr] = make_float2(psum[m][r], psq[m][r]);
            }
    }
    __syncthreads();
    float mean_[2][4], rstd_[2][4];
#pragma unroll
    for (int m = 0; m < 2; ++m)
#pragma unroll
        for (int r = 0; r < 4; ++r) {
            int lr = wr * 32 + m * 16 + ks * 4 + r;
            float2 a0 = lnb[lr], a1 = lnb[64 + lr];
            float mean = (a0.x + a1.x) * (1.f / 256.f);
            float var = (a0.y + a1.y) * (1.f / 256.f) - mean * mean;
            mean_[m][r] = mean;
            rstd_[m][r] = rsqrtf(var + 1e-5f);
        }
#pragma unroll
    for (int n = 0; n < 8; ++n) {
        int c = wc * 128 + n * 16 + rl;
        float gv = g3[c], bev = be3[c];
#pragma unroll
        for (int m = 0; m < 2; ++m)
#pragma unroll
            for (int r = 0; r < 4; ++r) {
                int grow = row0 + wr * 32 + m * 16 + ks * 4 + r;
                if (grow < N)
                    X[(size_t)grow * 256 + c] =
                        f2b((oacc[m][n][r] - mean_[m][r]) * rstd_[m][r] * gv + bev);
            }
    }
}

// ---------------------------------------------------------------------------
// GAT el/er projections, both node sets in one dispatch
// ---------------------------------------------------------------------------
__global__ void attn_lr_all_kernel(
    const ushort* __restrict__ h0, const float* __restrict__ al0, const float* __restrict__ ar0,
    float* __restrict__ el0, float* __restrict__ er0,
    const ushort* __restrict__ h1, const float* __restrict__ al1, const float* __restrict__ ar1,
    float* __restrict__ el1, float* __restrict__ er1)
{
    int idx = blockIdx.x * blockDim.x + threadIdx.x;
    if (idx >= 480000) return;
    const ushort* h; const float *a1, *a2; float *el, *er; int i;
    if (idx < 320000) { h = h0; a1 = al0; a2 = ar0; el = el0; er = er0; i = idx; }
    else { h = h1; a1 = al1; a2 = ar1; el = el1; er = er1; i = idx - 320000; }
    int hd = i & 7;
    const ushort* hp = h + (size_t)(i >> 3) * 256 + hd * 32;
    const float* p1 = a1 + hd * 32;
    const float* p2 = a2 + hd * 32;
    float s1 = 0.f, s2 = 0.f;
#pragma unroll
    for (int j = 0; j < 8; ++j) {
        ushort4 t = ((const ushort4*)hp)[j];
        float v0 = b2f(t.x), v1 = b2f(t.y), v2 = b2f(t.z), v3 = b2f(t.w);
        s1 = fmaf(v0, p1[j * 4 + 0], s1); s2 = fmaf(v0, p2[j * 4 + 0], s2);
        s1 = fmaf(v1, p1[j * 4 + 1], s1); s2 = fmaf(v1, p2[j * 4 + 1], s2);
        s1 = fmaf(v2, p1[j * 4 + 2], s1); s2 = fmaf(v2, p2[j * 4 + 2], s2);
        s1 = fmaf(v3, p1[j * 4 + 3], s1); s2 = fmaf(v3, p2[j * 4 + 3], s2);
    }
    el[i] = s1;
    er[i] = s2;
}

// ---------------------------------------------------------------------------
// CSR build: dual count; 2-stage scan (parts-prefix folded into final); scatter
// ---------------------------------------------------------------------------
__global__ void count2_kernel(const int* __restrict__ d0, int* __restrict__ c0,
                              const int* __restrict__ d1, int* __restrict__ c1, int E)
{
    int e = blockIdx.x * blockDim.x + threadIdx.x;
    if (e < E) atomicAdd(&c0[d0[e]], 1);
    else if (e < 2 * E) atomicAdd(&c1[d1[e - E]], 1);
}

__global__ void scan_chunk_kernel(const int* __restrict__ deg0, int* __restrict__ offs0,
                                  const int* __restrict__ deg1, int* __restrict__ offs1,
                                  int* __restrict__ parts, int N)
{
    int es = blockIdx.x / 20, ch = blockIdx.x % 20;
    const int* deg = es ? deg1 : deg0;
    int* offs = es ? offs1 : offs0;
    __shared__ int sbuf[1024];
    int tid = threadIdx.x;
    int i = ch * 1024 + tid;
    int v = (i < N) ? deg[i] : 0;
    sbuf[tid] = v;
    __syncthreads();
    for (int off = 1; off < 1024; off <<= 1) {
        int t = (tid >= off) ? sbuf[tid - off] : 0;
        __syncthreads();
        sbuf[tid] += t;
        __syncthreads();
    }
    if (i < N) offs[i] = sbuf[tid] - v;
    if (tid == 1023) parts[es * 21 + ch] = sbuf[1023];   // raw chunk total
}

__global__ void scan_final_kernel(int* __restrict__ deg0, int* __restrict__ offs0,
                                  int* __restrict__ deg1, int* __restrict__ offs1,
                                  const int* __restrict__ parts, int N)
{
    int es = blockIdx.x / 20, ch = blockIdx.x % 20;
    int* deg = es ? deg1 : deg0;
    int* offs = es ? offs1 : offs0;
    __shared__ int base_s, tot_s;
    int tid = threadIdx.x;
    if (tid == 0) {
        const int* p = parts + es * 21;
        int acc = 0, base = 0;
        for (int i = 0; i < 20; ++i) { if (i == ch) base = acc; acc += p[i]; }
        base_s = base;
        tot_s = acc;
    }
    __syncthreads();
    int i = ch * 1024 + tid;
    if (i < N) { offs[i] += base_s; deg[i] = 0; }
    if (ch == 19 && tid == 1023) offs[N] = tot_s;
}

__global__ void scatter2_kernel(const int* __restrict__ s0, const int* __restrict__ d0,
                                const int* __restrict__ o0, int* __restrict__ c0, int* __restrict__ l0,
                                const int* __restrict__ s1, const int* __restrict__ d1,
                                const int* __restrict__ o1, int* __restrict__ c1, int* __restrict__ l1,
                                int E)
{
    int e = blockIdx.x * blockDim.x + threadIdx.x;
    if (e < E) {
        int d = d0[e];
        int pos = atomicAdd(&c0[d], 1);
        l0[o0[d] + pos] = s0[e];
    } else if (e < 2 * E) {
        int e1 = e - E;
        int d = d1[e1];
        int pos = atomicAdd(&c1[d], 1);
        l1[o1[d] + pos] = s1[e1];
    }
}

// ---------------------------------------------------------------------------
// GAT aggregation, both edge sets: blocks [0,20000) = ap, [20000,40000) = pp
// ---------------------------------------------------------------------------
__global__ __launch_bounds__(64) void gat_agg_all_kernel(
    const ushort* __restrict__ ha, const float* __restrict__ ela, const float* __restrict__ era,
    const int* __restrict__ offsa, const int* __restrict__ lista, const float* __restrict__ biasa,
    const ushort* __restrict__ hp, const float* __restrict__ elp, const float* __restrict__ erp,
    const int* __restrict__ offsp, const int* __restrict__ listp, const float* __restrict__ biasp,
    ushort* __restrict__ out)
{
    int bid = blockIdx.x;
    const ushort* h; const float *el, *er, *bias; const int *offs, *elist;
    int p, dn, coloff;
    if (bid < NP_N) {
        h = ha; el = ela; er = era; offs = offsa; elist = lista; bias = biasa;
        p = bid; dn = NA_N + p; coloff = 256;
    } else {
        h = hp; el = elp; er = erp; offs = offsp; elist = listp; bias = biasp;
        p = bid - NP_N; dn = p; coloff = 512;
    }
    int l = threadIdx.x;
    int head = l >> 3;
    float erv = er[(size_t)dn * 8 + head];
    float acc[4] = {0.f, 0.f, 0.f, 0.f};
    float z = 0.f;
    int beg = offs[p], end = offs[p + 1];
    for (int e = beg - 1; e < end; ++e) {
        int s = (e < beg) ? dn : elist[e];
        float x = el[(size_t)s * 8 + head] + erv;
        x = x > 0.f ? x : 0.2f * x;
        float wgt = expf(x);
        z += wgt;
        ushort4 hv = *(const ushort4*)&h[(size_t)s * 256 + l * 4];
        acc[0] = fmaf(wgt, b2f(hv.x), acc[0]);
        acc[1] = fmaf(wgt, b2f(hv.y), acc[1]);
        acc[2] = fmaf(wgt, b2f(hv.z), acc[2]);
        acc[3] = fmaf(wgt, b2f(hv.w), acc[3]);
    }
    float inv = 1.f / z;
    ushort4 o;
    o.x = f2b(acc[0] * inv + bias[l * 4 + 0]);
    o.y = f2b(acc[1] * inv + bias[l * 4 + 1]);
    o.z = f2b(acc[2] * inv + bias[l * 4 + 2]);
    o.w = f2b(acc[3] * inv + bias[l * 4 + 3]);
    *(ushort4*)&out[(size_t)p * 768 + coloff + l * 4] = o;
}

// ---------------------------------------------------------------------------
// Tiny MHA (S=Sk=3). Writes output IN-PLACE over the q slice.
// ---------------------------------------------------------------------------
__global__ void mha3_kernel(const ushort* qb, int ldq, int qoff,
                            const ushort* kvb, int ldkv, int koff, int voff,
                            ushort* ob, int ldo, int NPn)
{
    int idx = blockIdx.x * blockDim.x + threadIdx.x;
    if (idx >= NPn * 24) return;
    int h = idx & 7;
    int i = (idx >> 3) % 3;
    int p = idx / 24;
    float qr[32];
    {
        const ushort* q = qb + (size_t)(p * 3 + i) * ldq + qoff + h * 32;
#pragma unroll
        for (int j = 0; j < 8; ++j) {
            ushort4 t = ((const ushort4*)q)[j];
            qr[j * 4 + 0] = b2f(t.x); qr[j * 4 + 1] = b2f(t.y);
            qr[j * 4 + 2] = b2f(t.z); qr[j * 4 + 3] = b2f(t.w);
        }
    }
    float s[3];
#pragma unroll
    for (int j = 0; j < 3; ++j) {
        const ushort* k = kvb + (size_t)(p * 3 + j) * ldkv + koff + h * 32;
        float a = 0.f;
#pragma unroll
        for (int t4 = 0; t4 < 8; ++t4) {
            ushort4 t = ((const ushort4*)k)[t4];
            a = fmaf(qr[t4 * 4 + 0], b2f(t.x), a);
            a = fmaf(qr[t4 * 4 + 1], b2f(t.y), a);
            a = fmaf(qr[t4 * 4 + 2], b2f(t.z), a);
            a = fmaf(qr[t4 * 4 + 3], b2f(t.w), a);
        }
        s[j] = a * 0.17677669529663687f;
    }
    float m = fmaxf(s[0], fmaxf(s[1], s[2]));
    float e0 = expf(s[0] - m), e1 = expf(s[1] - m), e2 = expf(s[2] - m);
    float inv = 1.f / (e0 + e1 + e2);
    float aw[3] = {e0 * inv, e1 * inv, e2 * inv};
    float o[32] = {};
#pragma unroll
    for (int j = 0; j < 3; ++j) {
        const ushort* v = kvb + (size_t)(p * 3 + j) * ldkv + voff + h * 32;
#pragma unroll
        for (int t4 = 0; t4 < 8; ++t4) {
            ushort4 t = ((const ushort4*)v)[t4];
            o[t4 * 4 + 0] = fmaf(aw[j], b2f(t.x), o[t4 * 4 + 0]);
            o[t4 * 4 + 1] = fmaf(aw[j], b2f(t.y), o[t4 * 4 + 1]);
            o[t4 * 4 + 2] = fmaf(aw[j], b2f(t.z), o[t4 * 4 + 2]);
            o[t4 * 4 + 3] = fmaf(aw[j], b2f(t.w), o[t4 * 4 + 3]);
        }
    }
    ushort* op = ob + (size_t)(p * 3 + i) * ldo + h * 32;
#pragma unroll
    for (int t4 = 0; t4 < 8; ++t4) {
        ushort4 t;
        t.x = f2b(o[t4 * 4 + 0]); t.y = f2b(o[t4 * 4 + 1]);
        t.z = f2b(o[t4 * 4 + 2]); t.w = f2b(o[t4 * 4 + 3]);
        ((ushort4*)op)[t4] = t;
    }
}

// ---------------------------------------------------------------------------
// kernel_launch — ws layout (bytes), total 184.32 MB (proven safe):
// [0, 30.72M) tgt_bf | [30.72M, 61.44M) X_bf | [61.44M, 65.28M) packed W
// [65.28M, 184.32M) BIG (era-overlaid)
// ---------------------------------------------------------------------------
extern "C" void kernel_launch(void* const* d_in, const int* in_sizes, int n_in,
                              void* d_out, int out_size, void* d_ws, size_t ws_size,
                              hipStream_t stream)
{
    const float* feat_paper  = (const float*)d_in[0];
    const float* feat_author = (const float*)d_in[1];
    const float* W_in_p  = (const float*)d_in[2];
    const float* b_in_p  = (const float*)d_in[3];
    const float* W_in_a  = (const float*)d_in[4];
    const float* b_in_a  = (const float*)d_in[5];
    const float* W_gat_ap = (const float*)d_in[6];
    const float* al_ap    = (const float*)d_in[7];
    const float* ar_ap    = (const float*)d_in[8];
    const float* b_gat_ap = (const float*)d_in[9];
    const float* W_gat_pp = (const float*)d_in[10];
    const float* al_pp    = (const float*)d_in[11];
    const float* ar_pp    = (const float*)d_in[12];
    const float* b_gat_pp = (const float*)d_in[13];
    const float* Wqkv_s = (const float*)d_in[14];
    const float* bqkv_s = (const float*)d_in[15];
    const float* Wo_s   = (const float*)d_in[16];
    const float* bo_s   = (const float*)d_in[17];
    const float* Wqkv_c = (const float*)d_in[18];
    const float* bqkv_c = (const float*)d_in[19];
    const float* Wo_c   = (const float*)d_in[20];
    const float* bo_c   = (const float*)d_in[21];
    const float* W_ff1  = (const float*)d_in[22];
    const float* b_ff1  = (const float*)d_in[23];
    const float* W_ff2  = (const float*)d_in[24];
    const float* b_ff2  = (const float*)d_in[25];
    const float* ln1_g  = (const float*)d_in[26];
    const float* ln1_b  = (const float*)d_in[27];
    const float* ln2_g  = (const float*)d_in[28];
    const float* ln2_b  = (const float*)d_in[29];
    const float* ln3_g  = (const float*)d_in[30];
    const float* ln3_b  = (const float*)d_in[31];
    const float* W_pred = (const float*)d_in[32];
    const float* b_pred = (const float*)d_in[33];
    const int* ap_src = (const int*)d_in[34];
    const int* ap_dst = (const int*)d_in[35];
    const int* pp_src = (const int*)d_in[36];
    const int* pp_dst = (const int*)d_in[37];

    const int NP = NP_N, NA = NA_N;

    uint8_t* wsb = (uint8_t*)d_ws;
    ushort* tgt_bf = (ushort*)wsb;
    ushort* X_bf   = (ushort*)(wsb + 30720000);
    ushort* WB     = (ushort*)(wsb + 61440000);
    ushort* p_in_p   = WB + 0;
    ushort* p_in_a   = WB + 32768;
    ushort* p_gat_ap = WB + 65536;
    ushort* p_gat_pp = WB + 131072;
    ushort* p_qkv_s  = WB + 196608;
    ushort* p_o_s    = WB + 393216;
    ushort* p_qkv_c  = WB + 458752;
    ushort* p_o_c    = WB + 655360;
    ushort* p_pred   = WB + 720896;
    ushort* p_ff1    = WB + 819200;
    ushort* p_ff2    = WB + 1343488;
    uint8_t* BIG = wsb + 65280000;

    // era A overlay inside BIG (hp lives directly in tgt slot 0)
    ushort* feat_p_bf = (ushort*)BIG;
    ushort* feat_a_bf = (ushort*)(BIG + 5120000);
    ushort* x_ap_bf   = (ushort*)(BIG + 10240000);   // authors only (20000,256)
    ushort* h_ap_bf   = (ushort*)(BIG + 30720000);
    ushort* h_pp_bf   = (ushort*)(BIG + 51200000);
    float* el_ap = (float*)(BIG + 61440000);
    float* er_ap = (float*)(BIG + 62720000);
    float* el_pp = (float*)(BIG + 64000000);
    float* er_pp = (float*)(BIG + 64640000);
    int* ireg    = (int*)(BIG + 65280000);
    int* ap_offs = ireg;
    int* pp_offs = ireg + 20004;
    int* ap_cur  = ireg + 40008;
    int* pp_cur  = ireg + 60008;
    int* ap_list = ireg + 80008;
    int* pp_list = ireg + 480008;
    int* parts   = ireg + 880008;   // [2][21]

    // ---- mega pack: converts + weight packs + counter zero, ONE dispatch ----
    {
        PackJobs J;
        const float* srcs[NJOBS] = { feat_paper, feat_author, W_in_p, W_in_a, W_gat_ap,
                                     W_gat_pp, Wqkv_s, Wo_s, Wqkv_c, Wo_c, W_pred,
                                     W_ff1, W_ff2, nullptr };
        void* dsts[NJOBS] = { feat_p_bf, feat_a_bf, p_in_p, p_in_a, p_gat_ap,
                              p_gat_pp, p_qkv_s, p_o_s, p_qkv_c, p_o_c, p_pred,
                              p_ff1, p_ff2, ap_cur };
        int Ms[NJOBS]  = {0,0, 256,256,256,256, 768,256,768,256, 64, 0,0, 0};
        int Ks[NJOBS]  = {0,0, 128,128,256,256, 256,256,256,256, 768, 0,0, 0};
        int tys[NJOBS] = {3,3, 0,0,0,0, 0,0,0,0, 0, 1,2, 4};
        int nq[NJOBS]  = {640000,640000, 8192,8192,16384,16384, 49152,16384,49152,16384,
                          24576, 131072,131072, 10000};
        int acc = 0;
        for (int j = 0; j < NJOBS; ++j) {
            J.src[j] = srcs[j]; J.dst[j] = dsts[j];
            J.M[j] = Ms[j]; J.K[j] = Ks[j]; J.type[j] = tys[j]; J.nquad[j] = nq[j];
            J.blk0[j] = acc;
            acc += (nq[j] + 255) / 256;
        }
        pack_all_kernel<<<acc, 256, 0, stream>>>(J);
    }

    // ---- batch 1: input projections (authors -> x_ap; papers -> tgt[:,0,:]) ----
    {
        GemmJobs G;
        G.njobs = 2;
        G.A[0] = feat_a_bf; G.Bp[0] = p_in_a; G.bias[0] = b_in_a; G.C[0] = x_ap_bf;
        G.N[0] = NA; G.M[0] = 256; G.K[0] = 128; G.lda[0] = 128; G.ldc[0] = 256;
        G.A[1] = feat_p_bf; G.Bp[1] = p_in_p; G.bias[1] = b_in_p; G.C[1] = tgt_bf;
        G.N[1] = NP; G.M[1] = 256; G.K[1] = 128; G.lda[1] = 128; G.ldc[1] = 768;
        int acc = 0;
        for (int j = 0; j < 2; ++j) {
            G.nbx[j] = (G.N[j] + 127) / 128;
            G.blk0[j] = acc;
            acc += G.nbx[j] * ((G.M[j] + 127) / 128);
        }
        gemm_batch_kernel<<<acc, 256, 0, stream>>>(G);
    }

    // ---- batch 2: GAT feature transforms (3 independent GEMMs) ----
    {
        GemmJobs G;
        G.njobs = 3;
        G.A[0] = x_ap_bf; G.Bp[0] = p_gat_ap; G.bias[0] = nullptr; G.C[0] = h_ap_bf;
        G.N[0] = NA; G.M[0] = 256; G.K[0] = 256; G.lda[0] = 256; G.ldc[0] = 256;
        G.A[1] = tgt_bf; G.Bp[1] = p_gat_ap; G.bias[1] = nullptr; G.C[1] = h_ap_bf + (size_t)NA * 256;
        G.N[1] = NP; G.M[1] = 256; G.K[1] = 256; G.lda[1] = 768; G.ldc[1] = 256;
        G.A[2] = tgt_bf; G.Bp[2] = p_gat_pp; G.bias[2] = nullptr; G.C[2] = h_pp_bf;
        G.N[2] = NP; G.M[2] = 256; G.K[2] = 256; G.lda[2] = 768; G.ldc[2] = 256;
        int acc = 0;
        for (int j = 0; j < 3; ++j) {
            G.nbx[j] = (G.N[j] + 127) / 128;
            G.blk0[j] = acc;
            acc += G.nbx[j] * ((G.M[j] + 127) / 128);
        }
        gemm_batch_kernel<<<acc, 256, 0, stream>>>(G);
    }

    // ---- el/er (one dispatch) ----
    attn_lr_all_kernel<<<1875, 256, 0, stream>>>(h_ap_bf, al_ap, ar_ap, el_ap, er_ap,
                                                 h_pp_bf, al_pp, ar_pp, el_pp, er_pp);

    // ---- CSR build (4 dispatches) ----
    count2_kernel<<<3125, 256, 0, stream>>>(ap_dst, ap_cur, pp_dst, pp_cur, E_AP_N);
    scan_chunk_kernel<<<40, 1024, 0, stream>>>(ap_cur, ap_offs, pp_cur, pp_offs, parts, NP);
    scan_final_kernel<<<40, 1024, 0, stream>>>(ap_cur, ap_offs, pp_cur, pp_offs, parts, NP);
    scatter2_kernel<<<3125, 256, 0, stream>>>(ap_src, ap_dst, ap_offs, ap_cur, ap_list,
                                              pp_src, pp_dst, pp_offs, pp_cur, pp_list, E_AP_N);

    // ---- GAT aggregation (one dispatch) ----
    gat_agg_all_kernel<<<2 * NP, 64, 0, stream>>>(
        h_ap_bf, el_ap, er_ap, ap_offs, ap_list, b_gat_ap,
        h_pp_bf, el_pp, er_pp, pp_offs, pp_list, b_gat_pp, tgt_bf);

    // ---- self attention, full 60000 rows ----
    {
        ushort* qkv = (ushort*)BIG;  // 92.16 MB
        gemm_bf(tgt_bf, p_qkv_s, bqkv_s, qkv, 60000, 768, 256, 256, 768, 0, stream);
        mha3_kernel<<<(NP * 24 + 255) / 256, 256, 0, stream>>>(qkv, 768, 0, qkv, 768, 256, 512, qkv, 768, NP);
        proj_ln_kernel<<<(60000 + 63) / 64, 256, 0, stream>>>(
            qkv, 768, p_o_s, bo_s, tgt_bf, 256, ln1_g, ln1_b, X_bf, 60000);
    }

    // ---- cross attention, full 60000 rows (q + kv batched) ----
    {
        ushort* qb  = (ushort*)BIG;                 // 30.72 MB
        ushort* kvb = (ushort*)(BIG + 30720000);    // 61.44 MB
        const ushort* p_kv_c = p_qkv_c + (size_t)2 * 8 * 4096;  // row-tiles 2..5
        GemmJobs G;
        G.njobs = 2;
        G.A[0] = X_bf; G.Bp[0] = p_qkv_c; G.bias[0] = bqkv_c; G.C[0] = qb;
        G.N[0] = 60000; G.M[0] = 256; G.K[0] = 256; G.lda[0] = 256; G.ldc[0] = 256;
        G.A[1] = tgt_bf; G.Bp[1] = p_kv_c; G.bias[1] = bqkv_c + 256; G.C[1] = kvb;
        G.N[1] = 60000; G.M[1] = 512; G.K[1] = 256; G.lda[1] = 256; G.ldc[1] = 512;
        int acc = 0;
        for (int j = 0; j < 2; ++j) {
            G.nbx[j] = (G.N[j] + 127) / 128;
            G.blk0[j] = acc;
            acc += G.nbx[j] * ((G.M[j] + 127) / 128);
        }
        gemm_batch_kernel<<<acc, 256, 0, stream>>>(G);
        mha3_kernel<<<(NP * 24 + 255) / 256, 256, 0, stream>>>(qb, 256, 0, kvb, 512, 0, 256, qb, 256, NP);
        proj_ln_kernel<<<(60000 + 63) / 64, 256, 0, stream>>>(
            qb, 256, p_o_c, bo_c, X_bf, 256, ln2_g, ln2_b, X_bf, 60000);
    }

    // ---- feed-forward + residual + LN3 fused (v8, measured optimum) ----
    ff_ln_kernel<<<(60000 + 63) / 64, 256, 0, stream>>>(p_ff1, p_ff2, b_ff1, b_ff2,
                                                        ln3_g, ln3_b, X_bf, 60000);

    // ---- prediction head ----
    gemm_bf(X_bf, p_pred, b_pred, (float*)d_out, NP, 64, 768, 768, 64, 1, stream);
}